// Round 1
// baseline (984.180 us; speedup 1.0000x reference)
//
#include <hip/hip_runtime.h>

#define DDIM 256
#define NROWS 16384
#define KCB 8192
#define BM 128
#define BN 128
#define BD 32
#define KSPLIT 4
#define KC (KCB / KSPLIT)            // 2048 codes per split
#define NTILES (KC / BN)             // 16 codebook tiles per split
#define NCHUNK (NTILES * (DDIM / BD)) // 128 staged chunks
#define ND (NROWS * DDIM)            // 4194304

// ---------------- codebook norms ----------------
__global__ void k_norms(const float* __restrict__ cb, float* __restrict__ norms) {
    const int wave = threadIdx.x >> 6, lane = threadIdx.x & 63;
    const int row = blockIdx.x * 4 + wave;
    float4 v = *reinterpret_cast<const float4*>(cb + (size_t)row * DDIM + lane * 4);
    float s = v.x * v.x + v.y * v.y + v.z * v.z + v.w * v.w;
#pragma unroll
    for (int off = 32; off > 0; off >>= 1) s += __shfl_xor(s, off, 64);
    if (lane == 0) norms[row] = s;
}

// ---------------- main GEMM-argmin ----------------
// score(n,k) = ||e_k||^2 - 2 * z_n . e_k   (||z||^2 dropped: row-constant)
__launch_bounds__(256, 2)
__global__ void k_argmin(const float* __restrict__ z, const float* __restrict__ cb,
                         const float* __restrict__ norms,
                         float* __restrict__ cand_val, int* __restrict__ cand_idx) {
    __shared__ float aS[2][BD][BM];   // 32 KB  [d][row]
    __shared__ float bS[2][BD][BN];   // 32 KB  [d][col]

    const int rb = blockIdx.x;        // row block (0..127)
    const int ks = blockIdx.y;        // codebook split (0..3)
    const int kbase = ks * KC;

    const int t = threadIdx.x;
    const int w = t >> 6, lane = t & 63;
    const int wr = w >> 1, wc = w & 1;       // wave quadrant in 128x128 tile
    const int tx = lane & 7, ty = lane >> 3; // 8x8 lane grid in 64x64 quadrant
    const int rowb = wr * 64 + ty * 8;
    const int colb = wc * 64 + tx * 8;

    // staging mapping: thread t loads float4 (d = 4*sc4..) of row srow0+32*rr
    const int sc4 = t & 7;
    const int srow0 = t >> 3;

    const float* zblk = z + (size_t)rb * BM * DDIM;

    float acc[8][8];
    float minv[8];
    int mini[8];
#pragma unroll
    for (int i = 0; i < 8; ++i) { minv[i] = 3.4e38f; mini[i] = 0; }

    float4 pa[4], pb[4];

    // prologue: stage chunk 0 into buffer 0
    {
        const float* asrc = zblk + (size_t)srow0 * DDIM + sc4 * 4;
        const float* bsrc = cb + (size_t)(kbase + srow0) * DDIM + sc4 * 4;
#pragma unroll
        for (int rr = 0; rr < 4; ++rr) {
            pa[rr] = *reinterpret_cast<const float4*>(asrc + (size_t)rr * 32 * DDIM);
            pb[rr] = *reinterpret_cast<const float4*>(bsrc + (size_t)rr * 32 * DDIM);
        }
#pragma unroll
        for (int rr = 0; rr < 4; ++rr) {
            const int r = srow0 + rr * 32;
            aS[0][sc4 * 4 + 0][r] = pa[rr].x; aS[0][sc4 * 4 + 1][r] = pa[rr].y;
            aS[0][sc4 * 4 + 2][r] = pa[rr].z; aS[0][sc4 * 4 + 3][r] = pa[rr].w;
            bS[0][sc4 * 4 + 0][r] = pb[rr].x; bS[0][sc4 * 4 + 1][r] = pb[rr].y;
            bS[0][sc4 * 4 + 2][r] = pb[rr].z; bS[0][sc4 * 4 + 3][r] = pb[rr].w;
        }
    }
    __syncthreads();

    for (int c = 0; c < NCHUNK; ++c) {
        const int p = c & 1;
        const int kt = c >> 3;
        const int dc = c & 7;
        if (dc == 0) {
#pragma unroll
            for (int i = 0; i < 8; ++i)
#pragma unroll
                for (int j = 0; j < 8; ++j) acc[i][j] = 0.f;
        }
        // prefetch next chunk into registers
        if (c + 1 < NCHUNK) {
            const int kt1 = (c + 1) >> 3, dc1 = (c + 1) & 7;
            const float* asrc = zblk + (size_t)srow0 * DDIM + dc1 * BD + sc4 * 4;
            const float* bsrc = cb + (size_t)(kbase + kt1 * BN + srow0) * DDIM + dc1 * BD + sc4 * 4;
#pragma unroll
            for (int rr = 0; rr < 4; ++rr) {
                pa[rr] = *reinterpret_cast<const float4*>(asrc + (size_t)rr * 32 * DDIM);
                pb[rr] = *reinterpret_cast<const float4*>(bsrc + (size_t)rr * 32 * DDIM);
            }
        }
        // compute current chunk
#pragma unroll 8
        for (int d = 0; d < BD; ++d) {
            float4 a0 = *reinterpret_cast<const float4*>(&aS[p][d][rowb]);
            float4 a1 = *reinterpret_cast<const float4*>(&aS[p][d][rowb + 4]);
            float4 b0 = *reinterpret_cast<const float4*>(&bS[p][d][colb]);
            float4 b1 = *reinterpret_cast<const float4*>(&bS[p][d][colb + 4]);
            float av[8] = {a0.x, a0.y, a0.z, a0.w, a1.x, a1.y, a1.z, a1.w};
            float bv[8] = {b0.x, b0.y, b0.z, b0.w, b1.x, b1.y, b1.z, b1.w};
#pragma unroll
            for (int i = 0; i < 8; ++i)
#pragma unroll
                for (int j = 0; j < 8; ++j)
                    acc[i][j] = fmaf(av[i], bv[j], acc[i][j]);
        }
        // write prefetched regs into the other buffer
        if (c + 1 < NCHUNK) {
            const int pn = p ^ 1;
#pragma unroll
            for (int rr = 0; rr < 4; ++rr) {
                const int r = srow0 + rr * 32;
                aS[pn][sc4 * 4 + 0][r] = pa[rr].x; aS[pn][sc4 * 4 + 1][r] = pa[rr].y;
                aS[pn][sc4 * 4 + 2][r] = pa[rr].z; aS[pn][sc4 * 4 + 3][r] = pa[rr].w;
                bS[pn][sc4 * 4 + 0][r] = pb[rr].x; bS[pn][sc4 * 4 + 1][r] = pb[rr].y;
                bS[pn][sc4 * 4 + 2][r] = pb[rr].z; bS[pn][sc4 * 4 + 3][r] = pb[rr].w;
            }
        }
        __syncthreads();
        // end of a codebook tile: fold norms, update running argmin (registers only)
        if (dc == 7) {
            const int k0 = kbase + kt * BN + colb;
            float4 n0 = *reinterpret_cast<const float4*>(norms + k0);
            float4 n1 = *reinterpret_cast<const float4*>(norms + k0 + 4);
            float nn[8] = {n0.x, n0.y, n0.z, n0.w, n1.x, n1.y, n1.z, n1.w};
#pragma unroll
            for (int i = 0; i < 8; ++i) {
#pragma unroll
                for (int j = 0; j < 8; ++j) {
                    float s = nn[j] - 2.f * acc[i][j];
                    if (s < minv[i]) { minv[i] = s; mini[i] = k0 + j; }
                }
            }
        }
    }

    // cross-thread argmin reduction: 16 column-group candidates per row
    __syncthreads();
    float* redv = reinterpret_cast<float*>(&aS[0][0][0]); // 128*16 floats = 8 KB
    int* redi = reinterpret_cast<int*>(&bS[0][0][0]);
    const int g = wc * 8 + tx; // 0..15 column group
#pragma unroll
    for (int i = 0; i < 8; ++i) {
        redv[(rowb + i) * 16 + g] = minv[i];
        redi[(rowb + i) * 16 + g] = mini[i];
    }
    __syncthreads();
    if (t < 128) {
        const int r = t;
        float bv = redv[r * 16];
        int bi = redi[r * 16];
#pragma unroll
        for (int g2 = 1; g2 < 16; ++g2) {
            float v = redv[r * 16 + g2];
            int k2 = redi[r * 16 + g2];
            if (v < bv || (v == bv && k2 < bi)) { bv = v; bi = k2; }
        }
        const int n = rb * BM + r;
        cand_val[n * KSPLIT + ks] = bv;
        cand_idx[n * KSPLIT + ks] = bi;
    }
}

// ---------------- merge the 4 K-splits ----------------
__global__ void k_merge(const float* __restrict__ cand_val, const int* __restrict__ cand_idx,
                        int* __restrict__ fidx) {
    const int n = blockIdx.x * blockDim.x + threadIdx.x;
    float bv = cand_val[n * KSPLIT];
    int bi = cand_idx[n * KSPLIT];
#pragma unroll
    for (int s = 1; s < KSPLIT; ++s) {
        float v = cand_val[n * KSPLIT + s];
        int i = cand_idx[n * KSPLIT + s];
        if (v < bv || (v == bv && i < bi)) { bv = v; bi = i; }
    }
    fidx[n] = bi;
}

// ---------------- copy z_e, gather z_q, loss partials ----------------
__global__ void k_finalize(const float* __restrict__ z, const float* __restrict__ cb,
                           const int* __restrict__ fidx, float* __restrict__ out,
                           float* __restrict__ partials) {
    const int i4 = blockIdx.x * blockDim.x + threadIdx.x; // float4 id, ND/4 total
    float4 zv = *reinterpret_cast<const float4*>(z + (size_t)i4 * 4);
    *reinterpret_cast<float4*>(out + (size_t)i4 * 4) = zv; // z_e copy (aligned)
    const int n = i4 >> 6;
    const int d0 = (i4 & 63) << 2;
    const int idx = fidx[n];
    float4 q = *reinterpret_cast<const float4*>(cb + (size_t)idx * DDIM + d0);
    float* oq = out + (size_t)ND + 1 + (size_t)i4 * 4; // odd offset -> scalar stores
    oq[0] = q.x; oq[1] = q.y; oq[2] = q.z; oq[3] = q.w;
    const float dx = q.x - zv.x, dy = q.y - zv.y, dz = q.z - zv.z, dw = q.w - zv.w;
    float s = dx * dx + dy * dy + dz * dz + dw * dw;
#pragma unroll
    for (int off = 32; off > 0; off >>= 1) s += __shfl_xor(s, off, 64);
    __shared__ float sm[4];
    const int wv = threadIdx.x >> 6, ln = threadIdx.x & 63;
    if (ln == 0) sm[wv] = s;
    __syncthreads();
    if (threadIdx.x == 0) partials[blockIdx.x] = sm[0] + sm[1] + sm[2] + sm[3];
}

__global__ void k_loss(const float* __restrict__ partials, float* __restrict__ out) {
    float s = 0.f;
    for (int i = threadIdx.x; i < 4096; i += 256) s += partials[i];
#pragma unroll
    for (int off = 32; off > 0; off >>= 1) s += __shfl_xor(s, off, 64);
    __shared__ float sm[4];
    const int wv = threadIdx.x >> 6, ln = threadIdx.x & 63;
    if (ln == 0) sm[wv] = s;
    __syncthreads();
    if (threadIdx.x == 0) out[ND] = 2.0f * (sm[0] + sm[1] + sm[2] + sm[3]) / (float)ND;
}

extern "C" void kernel_launch(void* const* d_in, const int* in_sizes, int n_in,
                              void* d_out, int out_size, void* d_ws, size_t ws_size,
                              hipStream_t stream) {
    const float* z = (const float*)d_in[0];   // [16384, 256]
    const float* cb = (const float*)d_in[1];  // [8192, 256]
    float* out = (float*)d_out;               // z_e[ND], loss[1], z_q[ND]
    float* ws = (float*)d_ws;

    float* norms = ws;                                   // 8192
    float* cand_val = ws + 8192;                         // 16384*4
    int* cand_idx = (int*)(ws + 8192 + 65536);           // 16384*4
    int* fidx = (int*)(ws + 8192 + 65536 + 65536);       // 16384
    float* partials = ws + 8192 + 65536 + 65536 + 16384; // 4096

    k_norms<<<dim3(2048), dim3(256), 0, stream>>>(cb, norms);
    k_argmin<<<dim3(128, 4), dim3(256), 0, stream>>>(z, cb, norms, cand_val, cand_idx);
    k_merge<<<dim3(64), dim3(256), 0, stream>>>(cand_val, cand_idx, fidx);
    k_finalize<<<dim3(4096), dim3(256), 0, stream>>>(z, cb, fidx, out, partials);
    k_loss<<<dim3(1), dim3(256), 0, stream>>>(partials, out);
}

// Round 3
// 347.000 us; speedup vs baseline: 2.8362x; 2.8362x over previous
//
#include <hip/hip_runtime.h>
#include <stdint.h>

typedef short short8 __attribute__((ext_vector_type(8)));
typedef float f32x4 __attribute__((ext_vector_type(4)));

#define DDIM 256
#define NROWS 16384
#define KCB 8192
#define KSPLIT 4
#define KC 2048
#define ND 4194304

// ---------------- bf16 RNE helpers ----------------
__device__ __forceinline__ unsigned short bf16_rne(float x) {
    unsigned u = __float_as_uint(x);
    unsigned r = (u + 0x7FFFu + ((u >> 16) & 1u)) >> 16;
    return (unsigned short)r;
}

// ---------------- split fp32 -> bf16 hi + lo ----------------
__global__ void k_split(const float* __restrict__ src, unsigned short* __restrict__ hi,
                        unsigned short* __restrict__ lo) {
    const int i = blockIdx.x * blockDim.x + threadIdx.x;
    float4 v = reinterpret_cast<const float4*>(src)[i];
    ushort4 h, l;
    h.x = bf16_rne(v.x); l.x = bf16_rne(v.x - __uint_as_float((unsigned)h.x << 16));
    h.y = bf16_rne(v.y); l.y = bf16_rne(v.y - __uint_as_float((unsigned)h.y << 16));
    h.z = bf16_rne(v.z); l.z = bf16_rne(v.z - __uint_as_float((unsigned)h.z << 16));
    h.w = bf16_rne(v.w); l.w = bf16_rne(v.w - __uint_as_float((unsigned)h.w << 16));
    reinterpret_cast<ushort4*>(hi)[i] = h;
    reinterpret_cast<ushort4*>(lo)[i] = l;
}

// ---------------- codebook norms (fp32 exact) ----------------
__global__ void k_norms(const float* __restrict__ cb, float* __restrict__ norms) {
    const int wave = threadIdx.x >> 6, lane = threadIdx.x & 63;
    const int row = blockIdx.x * 4 + wave;
    float4 v = *reinterpret_cast<const float4*>(cb + (size_t)row * DDIM + lane * 4);
    float s = v.x * v.x + v.y * v.y + v.z * v.z + v.w * v.w;
#pragma unroll
    for (int off = 32; off > 0; off >>= 1) s += __shfl_xor(s, off, 64);
    if (lane == 0) norms[row] = s;
}

// ---------------- MFMA score + top-2 argmin ----------------
// approx score(n,k) = ||e_k||^2 - 2*(zh.eh + zh.el + zl.eh)
__launch_bounds__(256, 2)
__global__ void k_score(const unsigned short* __restrict__ zh, const unsigned short* __restrict__ zl,
                        const unsigned short* __restrict__ eh, const unsigned short* __restrict__ el,
                        const float* __restrict__ norms,
                        float* __restrict__ cand_val, int* __restrict__ cand_idx) {
    __shared__ char smem[65536];   // 2 buffers x {Ah,Al,Bh,Bl} x [128 rows][32 d] bf16

    const int rb = blockIdx.x;     // row block 0..127
    const int ks = blockIdx.y;     // codebook split 0..3
    const int t = threadIdx.x;
    const int w = t >> 6, lane = t & 63;
    const int wr = w >> 1, wc = w & 1;       // wave quadrant
    const int l15 = lane & 15, l4 = lane >> 4;

    // staging: thread t handles rows {t>>2, t>>2+64}, 16B chunk kg=t&3, all 4 arrays
    const int srow = t >> 2, skg = t & 3;
    const size_t abase = ((size_t)(rb * 128 + srow)) * DDIM + skg * 8;
    const int swo = srow * 64 + skg * 16;    // LDS byte offset within an array

    f32x4 acc[4][4];
    float v1[16], v2[16];
    int i1[16], i2[16];
#pragma unroll
    for (int q = 0; q < 16; ++q) { v1[q] = 3.4e38f; v2[q] = 3.4e38f; i1[q] = 0; i2[q] = 0; }

    // ---- prologue: stage step 0 (ct=0, dc=0) into buffer 0 ----
    {
        const size_t bbase = ((size_t)(ks * KC + srow)) * DDIM + skg * 8;
        float4 f0 = *reinterpret_cast<const float4*>(zh + abase);
        float4 f1 = *reinterpret_cast<const float4*>(zh + abase + (size_t)64 * DDIM);
        float4 f2 = *reinterpret_cast<const float4*>(zl + abase);
        float4 f3 = *reinterpret_cast<const float4*>(zl + abase + (size_t)64 * DDIM);
        float4 f4 = *reinterpret_cast<const float4*>(eh + bbase);
        float4 f5 = *reinterpret_cast<const float4*>(eh + bbase + (size_t)64 * DDIM);
        float4 f6 = *reinterpret_cast<const float4*>(el + bbase);
        float4 f7 = *reinterpret_cast<const float4*>(el + bbase + (size_t)64 * DDIM);
        char* buf = smem;
        *reinterpret_cast<float4*>(buf + 0     + swo) = f0;
        *reinterpret_cast<float4*>(buf + 0     + swo + 4096) = f1;
        *reinterpret_cast<float4*>(buf + 8192  + swo) = f2;
        *reinterpret_cast<float4*>(buf + 8192  + swo + 4096) = f3;
        *reinterpret_cast<float4*>(buf + 16384 + swo) = f4;
        *reinterpret_cast<float4*>(buf + 16384 + swo + 4096) = f5;
        *reinterpret_cast<float4*>(buf + 24576 + swo) = f6;
        *reinterpret_cast<float4*>(buf + 24576 + swo + 4096) = f7;
    }
    __syncthreads();

    float4 pf[8];
    for (int step = 0; step < 128; ++step) {
        const int p = step & 1;
        const int ct = step >> 3, dc = step & 7;
        if (dc == 0) {
#pragma unroll
            for (int fm = 0; fm < 4; ++fm)
#pragma unroll
                for (int fn = 0; fn < 4; ++fn) acc[fm][fn] = (f32x4){0.f, 0.f, 0.f, 0.f};
        }
        // prefetch next step into registers
        if (step + 1 < 128) {
            const int ct1 = (step + 1) >> 3, dc1 = (step + 1) & 7;
            const size_t ao = abase + dc1 * 32;
            const size_t bo = ((size_t)(ks * KC + ct1 * 128 + srow)) * DDIM + dc1 * 32 + skg * 8;
            pf[0] = *reinterpret_cast<const float4*>(zh + ao);
            pf[1] = *reinterpret_cast<const float4*>(zh + ao + (size_t)64 * DDIM);
            pf[2] = *reinterpret_cast<const float4*>(zl + ao);
            pf[3] = *reinterpret_cast<const float4*>(zl + ao + (size_t)64 * DDIM);
            pf[4] = *reinterpret_cast<const float4*>(eh + bo);
            pf[5] = *reinterpret_cast<const float4*>(eh + bo + (size_t)64 * DDIM);
            pf[6] = *reinterpret_cast<const float4*>(el + bo);
            pf[7] = *reinterpret_cast<const float4*>(el + bo + (size_t)64 * DDIM);
        }
        // compute on current buffer
        {
            const char* cbuf = smem + p * 32768;
            short8 a_h[4], a_l[4];
#pragma unroll
            for (int fm = 0; fm < 4; ++fm) {
                const int ro = (wr * 64 + fm * 16 + l15) * 64 + l4 * 16;
                a_h[fm] = *reinterpret_cast<const short8*>(cbuf + ro);
                a_l[fm] = *reinterpret_cast<const short8*>(cbuf + 8192 + ro);
            }
#pragma unroll
            for (int fn = 0; fn < 4; ++fn) {
                const int co = (wc * 64 + fn * 16 + l15) * 64 + l4 * 16;
                short8 b_h = *reinterpret_cast<const short8*>(cbuf + 16384 + co);
                short8 b_l = *reinterpret_cast<const short8*>(cbuf + 24576 + co);
#pragma unroll
                for (int fm = 0; fm < 4; ++fm) {
                    acc[fm][fn] = __builtin_amdgcn_mfma_f32_16x16x32_bf16(a_h[fm], b_h, acc[fm][fn], 0, 0, 0);
                    acc[fm][fn] = __builtin_amdgcn_mfma_f32_16x16x32_bf16(a_h[fm], b_l, acc[fm][fn], 0, 0, 0);
                    acc[fm][fn] = __builtin_amdgcn_mfma_f32_16x16x32_bf16(a_l[fm], b_h, acc[fm][fn], 0, 0, 0);
                }
            }
        }
        // end of codebook tile: fold norms, per-lane pre-min over 4 cols, top2 update
        if (dc == 7) {
            const int cbase = ks * KC + ct * 128 + wc * 64 + l15;
            float nn0 = norms[cbase], nn1 = norms[cbase + 16];
            float nn2 = norms[cbase + 32], nn3 = norms[cbase + 48];
#pragma unroll
            for (int fm = 0; fm < 4; ++fm)
#pragma unroll
                for (int r = 0; r < 4; ++r) {
                    float s0 = fmaf(-2.f, acc[fm][0][r], nn0);
                    float s1 = fmaf(-2.f, acc[fm][1][r], nn1);
                    float s2 = fmaf(-2.f, acc[fm][2][r], nn2);
                    float s3 = fmaf(-2.f, acc[fm][3][r], nn3);
                    float sm = s0; int sj = cbase;
                    if (s1 < sm) { sm = s1; sj = cbase + 16; }
                    if (s2 < sm) { sm = s2; sj = cbase + 32; }
                    if (s3 < sm) { sm = s3; sj = cbase + 48; }
                    const int q = fm * 4 + r;
                    if (sm < v1[q]) { v2[q] = v1[q]; i2[q] = i1[q]; v1[q] = sm; i1[q] = sj; }
                    else if (sm < v2[q]) { v2[q] = sm; i2[q] = sj; }
                }
        }
        // write prefetched regs into other buffer
        if (step + 1 < 128) {
            char* buf = smem + (p ^ 1) * 32768;
            *reinterpret_cast<float4*>(buf + 0     + swo) = pf[0];
            *reinterpret_cast<float4*>(buf + 0     + swo + 4096) = pf[1];
            *reinterpret_cast<float4*>(buf + 8192  + swo) = pf[2];
            *reinterpret_cast<float4*>(buf + 8192  + swo + 4096) = pf[3];
            *reinterpret_cast<float4*>(buf + 16384 + swo) = pf[4];
            *reinterpret_cast<float4*>(buf + 16384 + swo + 4096) = pf[5];
            *reinterpret_cast<float4*>(buf + 24576 + swo) = pf[6];
            *reinterpret_cast<float4*>(buf + 24576 + swo + 4096) = pf[7];
        }
        __syncthreads();
    }

    // ---- butterfly top2 merge across the 16 column-lanes ----
#pragma unroll
    for (int m = 1; m < 16; m <<= 1) {
#pragma unroll
        for (int q = 0; q < 16; ++q) {
            float ov1 = __shfl_xor(v1[q], m, 64); int oi1 = __shfl_xor(i1[q], m, 64);
            float ov2 = __shfl_xor(v2[q], m, 64); int oi2 = __shfl_xor(i2[q], m, 64);
            bool bl = (ov1 < v1[q]) || (ov1 == v1[q] && oi1 < i1[q]);
            float fv = bl ? ov1 : v1[q]; int fi = bl ? oi1 : i1[q];
            float rv = bl ? v1[q] : ov1; int ri = bl ? i1[q] : oi1;
            float sv = bl ? ov2 : v2[q]; int si = bl ? oi2 : i2[q];
            bool b2 = (sv < rv) || (sv == rv && si < ri);
            v1[q] = fv; i1[q] = fi;
            v2[q] = b2 ? sv : rv; i2[q] = b2 ? si : ri;
        }
    }
    // write per-(row, colwave) merged top2 to LDS  (tiles are dead: all waves past final barrier)
    if (l15 == 0) {
#pragma unroll
        for (int q = 0; q < 16; ++q) {
            const int fm = q >> 2, r = q & 3;
            const int row128 = wr * 64 + fm * 16 + l4 * 4 + r;
            reinterpret_cast<int4*>(smem)[row128 * 2 + wc] =
                make_int4(__float_as_int(v1[q]), i1[q], __float_as_int(v2[q]), i2[q]);
        }
    }
    __syncthreads();
    if (t < 128) {
        int4 A = reinterpret_cast<int4*>(smem)[t * 2 + 0];
        int4 B = reinterpret_cast<int4*>(smem)[t * 2 + 1];
        float a1 = __int_as_float(A.x), a2 = __int_as_float(A.z);
        int aj1 = A.y, aj2 = A.w;
        float b1 = __int_as_float(B.x), b2v = __int_as_float(B.z);
        int bj1 = B.y, bj2 = B.w;
        bool bl = (b1 < a1) || (b1 == a1 && bj1 < aj1);
        float f1 = bl ? b1 : a1; int fj1 = bl ? bj1 : aj1;
        float rv = bl ? a1 : b1; int rj = bl ? aj1 : bj1;
        float sv = bl ? b2v : a2; int sj = bl ? bj2 : aj2;
        bool c2 = (sv < rv) || (sv == rv && sj < rj);
        float f2 = c2 ? sv : rv; int fj2 = c2 ? sj : rj;
        const int n = rb * 128 + t;
        cand_val[n * 8 + ks * 2 + 0] = f1; cand_idx[n * 8 + ks * 2 + 0] = fj1;
        cand_val[n * 8 + ks * 2 + 1] = f2; cand_idx[n * 8 + ks * 2 + 1] = fj2;
    }
}

// ---------------- merge splits + exact fp32 rescore of top-2 ----------------
// one wave per row; grid must cover NROWS*64 threads = 4096 blocks of 256
__global__ void k_merge(const float* __restrict__ z, const float* __restrict__ cb,
                        const float* __restrict__ norms,
                        const float* __restrict__ cand_val, const int* __restrict__ cand_idx,
                        int* __restrict__ fidx) {
    const int gid = blockIdx.x * blockDim.x + threadIdx.x;
    const int wid = gid >> 6;          // row id 0..16383
    const int lane = threadIdx.x & 63;
    float v1 = 3.4e38f, v2 = 3.4e38f; int i1 = 0, i2 = 0;
#pragma unroll
    for (int c = 0; c < 8; ++c) {
        float v = cand_val[wid * 8 + c]; int i = cand_idx[wid * 8 + c];
        bool lt1 = (v < v1) || (v == v1 && i < i1);
        bool lt2 = (v < v2) || (v == v2 && i < i2);
        if (lt1) { v2 = v1; i2 = i1; v1 = v; i1 = i; }
        else if (lt2) { v2 = v; i2 = i; }
    }
    const float4 zq = *reinterpret_cast<const float4*>(z + (size_t)wid * DDIM + lane * 4);
    float d[2]; int ii[2] = { i1, i2 };
#pragma unroll
    for (int c = 0; c < 2; ++c) {
        const float4 e4 = *reinterpret_cast<const float4*>(cb + (size_t)ii[c] * DDIM + lane * 4);
        float s = zq.x * e4.x + zq.y * e4.y + zq.z * e4.z + zq.w * e4.w;
#pragma unroll
        for (int m = 32; m > 0; m >>= 1) s += __shfl_xor(s, m, 64);
        d[c] = norms[ii[c]] - 2.f * s;
    }
    const int best = (d[1] < d[0] || (d[1] == d[0] && ii[1] < ii[0])) ? ii[1] : ii[0];
    if (lane == 0) fidx[wid] = best;
}

// ---------------- copy z_e, gather z_q, loss partials ----------------
__global__ void k_finalize(const float* __restrict__ z, const float* __restrict__ cb,
                           const int* __restrict__ fidx, float* __restrict__ out,
                           float* __restrict__ partials) {
    const int i4 = blockIdx.x * blockDim.x + threadIdx.x;
    float4 zv = *reinterpret_cast<const float4*>(z + (size_t)i4 * 4);
    *reinterpret_cast<float4*>(out + (size_t)i4 * 4) = zv;
    const int n = i4 >> 6;
    const int d0 = (i4 & 63) << 2;
    const int idx = fidx[n];
    float4 q = *reinterpret_cast<const float4*>(cb + (size_t)idx * DDIM + d0);
    float* oq = out + (size_t)ND + 1 + (size_t)i4 * 4;
    oq[0] = q.x; oq[1] = q.y; oq[2] = q.z; oq[3] = q.w;
    const float dx = q.x - zv.x, dy = q.y - zv.y, dz = q.z - zv.z, dw = q.w - zv.w;
    float s = dx * dx + dy * dy + dz * dz + dw * dw;
#pragma unroll
    for (int off = 32; off > 0; off >>= 1) s += __shfl_xor(s, off, 64);
    __shared__ float sm[4];
    const int wv = threadIdx.x >> 6, ln = threadIdx.x & 63;
    if (ln == 0) sm[wv] = s;
    __syncthreads();
    if (threadIdx.x == 0) partials[blockIdx.x] = sm[0] + sm[1] + sm[2] + sm[3];
}

__global__ void k_loss(const float* __restrict__ partials, float* __restrict__ out) {
    float s = 0.f;
    for (int i = threadIdx.x; i < 4096; i += 256) s += partials[i];
#pragma unroll
    for (int off = 32; off > 0; off >>= 1) s += __shfl_xor(s, off, 64);
    __shared__ float sm[4];
    const int wv = threadIdx.x >> 6, ln = threadIdx.x & 63;
    if (ln == 0) sm[wv] = s;
    __syncthreads();
    if (threadIdx.x == 0) out[ND] = 2.0f * (sm[0] + sm[1] + sm[2] + sm[3]) / (float)ND;
}

extern "C" void kernel_launch(void* const* d_in, const int* in_sizes, int n_in,
                              void* d_out, int out_size, void* d_ws, size_t ws_size,
                              hipStream_t stream) {
    const float* z = (const float*)d_in[0];   // [16384, 256]
    const float* cb = (const float*)d_in[1];  // [8192, 256]
    float* out = (float*)d_out;               // z_e[ND], loss[1], z_q[ND]
    float* ws = (float*)d_ws;

    // small scratch in ws (~120 KB)
    float* norms = ws;                        // 8192
    int* fidx = (int*)(ws + 8192);            // 16384
    float* partials = ws + 8192 + 16384;      // 4096

    // big scratch carved from d_out (33.55 MB total; fully overwritten by k_finalize+k_loss)
    char* ob = (char*)d_out;
    unsigned short* zh = (unsigned short*)(ob);                     // 8.39 MB
    unsigned short* zl = (unsigned short*)(ob + 8388608);           // 8.39 MB
    unsigned short* eh = (unsigned short*)(ob + 16777216);          // 4.19 MB
    unsigned short* el = (unsigned short*)(ob + 20971520);          // 4.19 MB
    float* cand_val = (float*)(ob + 25165824);                      // 0.52 MB
    int* cand_idx = (int*)(ob + 25690112);                          // 0.52 MB (ends 26.2 MB < 33.5 MB)

    k_split<<<dim3(4096), dim3(256), 0, stream>>>(z, zh, zl);
    k_split<<<dim3(2048), dim3(256), 0, stream>>>(cb, eh, el);
    k_norms<<<dim3(2048), dim3(256), 0, stream>>>(cb, norms);
    k_score<<<dim3(128, 4), dim3(256), 0, stream>>>(zh, zl, eh, el, norms, cand_val, cand_idx);
    k_merge<<<dim3(4096), dim3(256), 0, stream>>>(z, cb, norms, cand_val, cand_idx, fidx);
    k_finalize<<<dim3(4096), dim3(256), 0, stream>>>(z, cb, fidx, out, partials);
    k_loss<<<dim3(1), dim3(256), 0, stream>>>(partials, out);
}